// Round 14
// baseline (911.759 us; speedup 1.0000x reference)
//
#include <hip/hip_runtime.h>
#include <hip/hip_fp16.h>

#define EMB 64
#define SCAN_TPB 256
#define SCAN_EPT 8
#define SCAN_ELEMS (SCAN_TPB * SCAN_EPT)  // 2048
#define SB 8                              // scatter batch depth

// Packed edge: (col << 13) | q, where val = q / 81920.0  (val in [0,0.1) per spec)
typedef unsigned int PEdge;
#define VAL_SCALE 81920.0f
#define VAL_INV   (1.0f / 81920.0f)

// Shard key for hist: cursor line granule (16 rows) -> one XCD owns each line.
__device__ __forceinline__ int row_shard(int r) { return (r >> 4) & 7; }

template <typename T>
__device__ __forceinline__ T ntload(const T* p) { return __builtin_nontemporal_load(p); }

// ---------- convert fp32 concat(ue,ie) -> fp16 x buffer ----------
__global__ void k_cvt(const float4* __restrict__ ue, const float4* __restrict__ ie,
                      __half2* __restrict__ xh2, long nu4, long ni4) {
    long total = nu4 + ni4;  // units of 4 floats
    long stride = (long)gridDim.x * blockDim.x;
    for (long i = (long)blockIdx.x * blockDim.x + threadIdx.x; i < total; i += stride) {
        float4 v = (i < nu4) ? ue[i] : ie[i - nu4];
        xh2[i * 2]     = __floats2half2_rn(v.x, v.y);
        xh2[i * 2 + 1] = __floats2half2_rn(v.z, v.w);
    }
}

// ---------- hist (XCD-sharded, fire-and-forget atomics) ----------
__global__ void k_hist(const int* __restrict__ rows, int* __restrict__ cnt, int ne) {
    int g  = blockIdx.x & 7;
    int lt = (blockIdx.x >> 3) * blockDim.x + threadIdx.x;
    int gs = (gridDim.x >> 3) * blockDim.x;
    for (int e = lt; e < ne; e += gs) {
        int r = ntload(rows + e);
        if (row_shard(r) == g) atomicAdd(&cnt[r], 1);
    }
}

// ---------- scatter: unsharded, batch-8 atomics (latency-hiding) ----------
// Phase a: load 8 edges into regs. Phase b: 8 independent atomicAdds issued
// back-to-back (returns only consumed in phase c -> all 8 in flight).
// Phase c: 8 stores. 8x outstanding atomic round-trips per wave.
__global__ void k_scatter(const int* __restrict__ rows, const int* __restrict__ cols,
                          const float* __restrict__ vals, int* __restrict__ cursor,
                          PEdge* __restrict__ pe, int ne) {
    long lt = (long)blockIdx.x * blockDim.x + threadIdx.x;
    long gs = (long)gridDim.x * blockDim.x;
    for (long e0 = lt; e0 < ne; e0 += SB * gs) {
        int rr[SB]; unsigned lo[SB]; bool m[SB];
#pragma unroll
        for (int k = 0; k < SB; ++k) {
            long e = e0 + (long)k * gs;
            bool ok = e < ne;
            int r = ok ? ntload(rows + e) : 0;
            unsigned c = 0, q = 0;
            if (ok) {
                float v = ntload(vals + e);
                c = (unsigned)ntload(cols + e);
                q = (unsigned)(v * VAL_SCALE + 0.5f);
                if (q > 8191u) q = 8191u;
            }
            m[k] = ok;
            rr[k] = r;
            lo[k] = (c << 13) | q;
        }
        int p[SB];
#pragma unroll
        for (int k = 0; k < SB; ++k)
            if (m[k]) p[k] = atomicAdd(&cursor[rr[k]], 1);
#pragma unroll
        for (int k = 0; k < SB; ++k)
            if (m[k]) pe[p[k]] = lo[k];
    }
}

__global__ void k_scan1(const int* __restrict__ in, int* __restrict__ excl,
                        int* __restrict__ bsums, int n) {
    __shared__ int sh[SCAN_TPB];
    int t = threadIdx.x;
    int base = blockIdx.x * SCAN_ELEMS + t * SCAN_EPT;
    int v[SCAN_EPT];
    int ts = 0;
#pragma unroll
    for (int k = 0; k < SCAN_EPT; ++k) {
        v[k] = (base + k < n) ? in[base + k] : 0;
        ts += v[k];
    }
    sh[t] = ts;
    __syncthreads();
    for (int off = 1; off < SCAN_TPB; off <<= 1) {
        int x = (t >= off) ? sh[t - off] : 0;
        __syncthreads();
        sh[t] += x;
        __syncthreads();
    }
    int run = sh[t] - ts;
#pragma unroll
    for (int k = 0; k < SCAN_EPT; ++k) {
        if (base + k < n) excl[base + k] = run;
        run += v[k];
    }
    if (t == SCAN_TPB - 1) bsums[blockIdx.x] = sh[t];
}

__global__ void k_scan2(const int* __restrict__ bsums, int* __restrict__ bexcl, int nb) {
    __shared__ int sh[SCAN_TPB];
    int t = threadIdx.x;
    int ts = (t < nb) ? bsums[t] : 0;
    sh[t] = ts;
    __syncthreads();
    for (int off = 1; off < SCAN_TPB; off <<= 1) {
        int x = (t >= off) ? sh[t - off] : 0;
        __syncthreads();
        sh[t] += x;
        __syncthreads();
    }
    if (t < nb) bexcl[t] = sh[t] - ts;
}

__global__ void k_scan3(int* __restrict__ row_start, int* __restrict__ cursor,
                        const int* __restrict__ bexcl, int n, int ne) {
    int base = blockIdx.x * SCAN_ELEMS + threadIdx.x * SCAN_EPT;
    int off = bexcl[blockIdx.x];
#pragma unroll
    for (int k = 0; k < SCAN_EPT; ++k) {
        if (base + k < n) {
            int v = row_start[base + k] + off;
            row_start[base + k] = v;
            cursor[base + k] = v;
        }
    }
    if (blockIdx.x == 0 && threadIdx.x == 0) row_start[n] = ne;
}

// ---------- SpMM mid layer: cached pe reads; pad slots reuse slot-0 (L1-hot) ----------
__global__ void k_spmm_mid(const int* __restrict__ row_start, const PEdge* __restrict__ pe,
                           const __half* __restrict__ x, __half* __restrict__ nxt, int n) {
    int wid = (int)(((long)blockIdx.x * blockDim.x + threadIdx.x) >> 6);
    int lane = threadIdx.x & 63;
    if (wid >= n) return;
    int s = row_start[wid];
    int e = row_start[wid + 1];
    float sum = 0.f;
    for (int j = s; j < e; j += 8) {
        int   cc[8];
        float vv[8];
#pragma unroll
        for (int k = 0; k < 8; ++k) {
            int jj = j + k;
            bool ok = jj < e;
            unsigned u = pe[ok ? jj : j];      // pad -> slot 0 of THIS block (L1-hot)
            cc[k] = (int)(u >> 13);
            vv[k] = ok ? (float)(u & 8191u) * VAL_INV : 0.f;
        }
        float xs[8];
#pragma unroll
        for (int k = 0; k < 8; ++k)
            xs[k] = __half2float(x[(size_t)cc[k] * EMB + lane]);
#pragma unroll
        for (int k = 0; k < 8; ++k) sum += vv[k] * xs[k];
    }
    size_t o = (size_t)wid * EMB + lane;
    short hs = __half_as_short(__float2half(sum));
    __builtin_nontemporal_store(hs, (short*)nxt + o);
}

// ---------- SpMM last layer: gather from x2 (=e2), combine all 4 layers ----------
__global__ void k_spmm_last(const int* __restrict__ row_start, const PEdge* __restrict__ pe,
                            const __half* __restrict__ x2, const __half* __restrict__ xh1,
                            const float* __restrict__ ue, const float* __restrict__ ie, int nu,
                            float* __restrict__ acc, int n) {
    int wid = (int)(((long)blockIdx.x * blockDim.x + threadIdx.x) >> 6);
    int lane = threadIdx.x & 63;
    if (wid >= n) return;
    int s = row_start[wid];
    int e = row_start[wid + 1];
    float sum = 0.f;
    for (int j = s; j < e; j += 8) {
        int   cc[8];
        float vv[8];
#pragma unroll
        for (int k = 0; k < 8; ++k) {
            int jj = j + k;
            bool ok = jj < e;
            unsigned u = pe[ok ? jj : j];
            cc[k] = (int)(u >> 13);
            vv[k] = ok ? (float)(u & 8191u) * VAL_INV : 0.f;
        }
        float xs[8];
#pragma unroll
        for (int k = 0; k < 8; ++k)
            xs[k] = __half2float(x2[(size_t)cc[k] * EMB + lane]);
#pragma unroll
        for (int k = 0; k < 8; ++k) sum += vv[k] * xs[k];
    }
    size_t o = (size_t)wid * EMB + lane;
    const float* p = (wid < nu) ? (ue + (size_t)wid * EMB) : (ie + (size_t)(wid - nu) * EMB);
    float e0 = p[lane];
    float e1 = __half2float(xh1[o]);
    float e2 = __half2float(x2[o]);
    float r = (e0 + e1 + e2 + sum) * 0.25f;
    __builtin_nontemporal_store(r, acc + o);
}

// ---------- fallback (R1 atomic path, fp32) ----------
__global__ void lgcn_init(const float4* __restrict__ ue, const float4* __restrict__ ie,
                          float4* __restrict__ emb, float4* __restrict__ acc,
                          long nu4, long ni4) {
    long total = nu4 + ni4;
    long stride = (long)gridDim.x * blockDim.x;
    for (long i = (long)blockIdx.x * blockDim.x + threadIdx.x; i < total; i += stride) {
        float4 v = (i < nu4) ? ue[i] : ie[i - nu4];
        emb[i] = v;
        acc[i] = v;
    }
}

__global__ void lgcn_spmm_atomic(const float* __restrict__ vals, const int* __restrict__ rows,
                                 const int* __restrict__ cols, const float* __restrict__ x,
                                 float* __restrict__ y, int ne) {
    long gid = (long)blockIdx.x * blockDim.x + threadIdx.x;
    int e = (int)(gid >> 6);
    int lane = (int)(gid & 63);
    if (e >= ne) return;
    float xv = x[(size_t)cols[e] * EMB + lane];
    atomicAdd(&y[(size_t)rows[e] * EMB + lane], vals[e] * xv);
}

__global__ void lgcn_acc(const float4* __restrict__ src, float4* __restrict__ acc,
                         long n4, float scale) {
    long stride = (long)gridDim.x * blockDim.x;
    for (long i = (long)blockIdx.x * blockDim.x + threadIdx.x; i < n4; i += stride) {
        float4 a = acc[i];
        float4 s = src[i];
        a.x = (a.x + s.x) * scale;
        a.y = (a.y + s.y) * scale;
        a.z = (a.z + s.z) * scale;
        a.w = (a.w + s.w) * scale;
        acc[i] = a;
    }
}

extern "C" void kernel_launch(void* const* d_in, const int* in_sizes, int n_in,
                              void* d_out, int out_size, void* d_ws, size_t ws_size,
                              hipStream_t stream) {
    const float* ue   = (const float*)d_in[0];
    const float* ie   = (const float*)d_in[1];
    const float* vals = (const float*)d_in[2];
    const int*   rows = (const int*)d_in[3];
    const int*   cols = (const int*)d_in[4];

    const int nu = in_sizes[0] / EMB;
    const int ni = in_sizes[1] / EMB;
    const int ne = in_sizes[2];
    const long n = (long)nu + ni;
    const size_t hbuf_bytes = (size_t)n * EMB * sizeof(__half);

    float* acc = (float*)d_out;

    // workspace carve
    char* p = (char*)d_ws;
    __half* xh0 = (__half*)p;    p += hbuf_bytes;
    __half* xh1 = (__half*)p;    p += hbuf_bytes;
    __half* xh2 = (__half*)p;    p += hbuf_bytes;
    PEdge* pe   = (PEdge*)p;     p += (size_t)ne * sizeof(PEdge);
    int*   row_start = (int*)p;  p += (size_t)(n + 1) * sizeof(int);
    int*   cursor = (int*)p;     p += (size_t)n * sizeof(int);
    int nb = (int)((n + SCAN_ELEMS - 1) / SCAN_ELEMS);
    int*   bsums = (int*)p;      p += (size_t)nb * sizeof(int);
    int*   bexcl = (int*)p;      p += (size_t)nb * sizeof(int);
    size_t needed = (size_t)(p - (char*)d_ws);

    const long nu4 = (long)nu * (EMB / 4);
    const long ni4 = (long)ni * (EMB / 4);

    if (needed <= ws_size && nb <= SCAN_TPB) {
        // ---- 1) CSR build (sharded hist; unsharded batch-8 scatter) ----
        (void)hipMemsetAsync(cursor, 0, (size_t)n * sizeof(int), stream);
        k_hist<<<2048, 256, 0, stream>>>(rows, cursor, ne);
        k_scan1<<<nb, SCAN_TPB, 0, stream>>>(cursor, row_start, bsums, (int)n);
        k_scan2<<<1, SCAN_TPB, 0, stream>>>(bsums, bexcl, nb);
        k_scan3<<<nb, SCAN_TPB, 0, stream>>>(row_start, cursor, bexcl, (int)n, ne);
        k_scatter<<<2048, 256, 0, stream>>>(rows, cols, vals, cursor, pe, ne);

        // ---- 2) fp16 buffers: defensive zero (call-invariance) + input cvt ----
        (void)hipMemsetAsync(xh0, 0, hbuf_bytes * 3, stream);
        k_cvt<<<2048, 256, 0, stream>>>((const float4*)ue, (const float4*)ie,
                                        (__half2*)xh0, nu4, ni4);

        // ---- 3) 3 SpMM layers; acc deferred entirely to the last kernel ----
        int blocks = (int)((n * 64 + 255) / 256);
        k_spmm_mid<<<blocks, 256, 0, stream>>>(row_start, pe, xh0, xh1, (int)n);
        k_spmm_mid<<<blocks, 256, 0, stream>>>(row_start, pe, xh1, xh2, (int)n);
        k_spmm_last<<<blocks, 256, 0, stream>>>(row_start, pe, xh2, xh1, ue, ie, nu,
                                                acc, (int)n);
    } else {
        // ---- fallback: R1 atomic path (fp32) ----
        const size_t buf_bytes = (size_t)n * EMB * sizeof(float);
        float* buf0 = (float*)d_ws;
        float* buf1 = (float*)((char*)d_ws + buf_bytes);
        const long n4 = n * (EMB / 4);
        lgcn_init<<<2048, 256, 0, stream>>>((const float4*)ue, (const float4*)ie,
                                            (float4*)buf0, (float4*)acc, nu4, ni4);
        float* cur = buf0;
        float* nxt = buf1;
        for (int l = 0; l < 3; ++l) {
            (void)hipMemsetAsync(nxt, 0, buf_bytes, stream);
            long threads = (long)ne * 64;
            int blk = (int)((threads + 255) / 256);
            lgcn_spmm_atomic<<<blk, 256, 0, stream>>>(vals, rows, cols, cur, nxt, ne);
            float scale = (l == 2) ? 0.25f : 1.0f;
            lgcn_acc<<<2048, 256, 0, stream>>>((const float4*)nxt, (float4*)acc, n4, scale);
            float* t = cur; cur = nxt; nxt = t;
        }
    }
}

// Round 15
// 670.572 us; speedup vs baseline: 1.3597x; 1.3597x over previous
//
#include <hip/hip_runtime.h>
#include <hip/hip_fp16.h>

#define EMB 64
#define SCAN_TPB 256
#define SCAN_EPT 8
#define SCAN_ELEMS (SCAN_TPB * SCAN_EPT)  // 2048

// Packed edge: (col << 13) | q, where val = q / 81920.0  (val in [0,0.1) per spec)
typedef unsigned int PEdge;
#define VAL_SCALE 81920.0f
#define VAL_INV   (1.0f / 81920.0f)

// Shard key: cursor line granule (16 rows) -> one XCD owns each line.
__device__ __forceinline__ int row_shard(int r) { return (r >> 4) & 7; }

template <typename T>
__device__ __forceinline__ T ntload(const T* p) { return __builtin_nontemporal_load(p); }

// ---------- convert fp32 concat(ue,ie) -> fp16 x buffer ----------
__global__ void k_cvt(const float4* __restrict__ ue, const float4* __restrict__ ie,
                      __half2* __restrict__ xh2, long nu4, long ni4) {
    long total = nu4 + ni4;  // units of 4 floats
    long stride = (long)gridDim.x * blockDim.x;
    for (long i = (long)blockIdx.x * blockDim.x + threadIdx.x; i < total; i += stride) {
        float4 v = (i < nu4) ? ue[i] : ie[i - nu4];
        xh2[i * 2]     = __floats2half2_rn(v.x, v.y);
        xh2[i * 2 + 1] = __floats2half2_rn(v.z, v.w);
    }
}

// ---------- CSR build (R13: XCD-sharded, nt streaming reads) ----------
__global__ void k_hist(const int* __restrict__ rows, int* __restrict__ cnt, int ne) {
    int g  = blockIdx.x & 7;
    int lt = (blockIdx.x >> 3) * blockDim.x + threadIdx.x;
    int gs = (gridDim.x >> 3) * blockDim.x;
    for (int e = lt; e < ne; e += gs) {
        int r = ntload(rows + e);
        if (row_shard(r) == g) atomicAdd(&cnt[r], 1);
    }
}

__global__ void k_scatter(const int* __restrict__ rows, const int* __restrict__ cols,
                          const float* __restrict__ vals, int* __restrict__ cursor,
                          PEdge* __restrict__ pe, int ne) {
    int g  = blockIdx.x & 7;
    int lt = (blockIdx.x >> 3) * blockDim.x + threadIdx.x;
    int gs = (gridDim.x >> 3) * blockDim.x;
    for (int e = lt; e < ne; e += gs) {
        int r = ntload(rows + e);
        if (row_shard(r) == g) {
            int p = atomicAdd(&cursor[r], 1);
            unsigned q = (unsigned)(ntload(vals + e) * VAL_SCALE + 0.5f);
            if (q > 8191u) q = 8191u;
            pe[p] = ((unsigned)ntload(cols + e) << 13) | q;
        }
    }
}

__global__ void k_scan1(const int* __restrict__ in, int* __restrict__ excl,
                        int* __restrict__ bsums, int n) {
    __shared__ int sh[SCAN_TPB];
    int t = threadIdx.x;
    int base = blockIdx.x * SCAN_ELEMS + t * SCAN_EPT;
    int v[SCAN_EPT];
    int ts = 0;
#pragma unroll
    for (int k = 0; k < SCAN_EPT; ++k) {
        v[k] = (base + k < n) ? in[base + k] : 0;
        ts += v[k];
    }
    sh[t] = ts;
    __syncthreads();
    for (int off = 1; off < SCAN_TPB; off <<= 1) {
        int x = (t >= off) ? sh[t - off] : 0;
        __syncthreads();
        sh[t] += x;
        __syncthreads();
    }
    int run = sh[t] - ts;
#pragma unroll
    for (int k = 0; k < SCAN_EPT; ++k) {
        if (base + k < n) excl[base + k] = run;
        run += v[k];
    }
    if (t == SCAN_TPB - 1) bsums[blockIdx.x] = sh[t];
}

__global__ void k_scan2(const int* __restrict__ bsums, int* __restrict__ bexcl, int nb) {
    __shared__ int sh[SCAN_TPB];
    int t = threadIdx.x;
    int ts = (t < nb) ? bsums[t] : 0;
    sh[t] = ts;
    __syncthreads();
    for (int off = 1; off < SCAN_TPB; off <<= 1) {
        int x = (t >= off) ? sh[t - off] : 0;
        __syncthreads();
        sh[t] += x;
        __syncthreads();
    }
    if (t < nb) bexcl[t] = sh[t] - ts;
}

__global__ void k_scan3(int* __restrict__ row_start, int* __restrict__ cursor,
                        const int* __restrict__ bexcl, int n, int ne) {
    int base = blockIdx.x * SCAN_ELEMS + threadIdx.x * SCAN_EPT;
    int off = bexcl[blockIdx.x];
#pragma unroll
    for (int k = 0; k < SCAN_EPT; ++k) {
        if (base + k < n) {
            int v = row_start[base + k] + off;
            row_start[base + k] = v;
            cursor[base + k] = v;
        }
    }
    if (blockIdx.x == 0 && threadIdx.x == 0) row_start[n] = ne;
}

// ---------- SpMM: TWO rows per wave (32-lane halves, __half2 = 2 dims/lane) ----------
// One gather instruction serves both rows -> ~1.7x fewer issue slots; line
// traffic unchanged. Pad slots reuse slot-0 of the current block (L1-hot).
__global__ void k_spmm_mid(const int* __restrict__ row_start, const PEdge* __restrict__ pe,
                           const __half* __restrict__ x, __half* __restrict__ nxt, int n) {
    long gid = (long)blockIdx.x * blockDim.x + threadIdx.x;
    int wave = (int)(gid >> 6);
    int lane = threadIdx.x & 63;
    int half = lane >> 5;
    int l32  = lane & 31;
    int r = wave * 2 + half;
    if (wave * 2 >= n) return;
    bool valid = r < n;
    int rc = valid ? r : n - 1;
    int s = row_start[rc];
    int e = row_start[rc + 1];
    float sx = 0.f, sy = 0.f;
    for (int j = s; j < e; j += 8) {
        int cc[8]; float vv[8];
#pragma unroll
        for (int k = 0; k < 8; ++k) {
            int jj = j + k;
            bool ok = jj < e;
            unsigned u = pe[ok ? jj : j];
            cc[k] = (int)(u >> 13);
            vv[k] = ok ? (float)(u & 8191u) * VAL_INV : 0.f;
        }
        __half2 xs[8];
#pragma unroll
        for (int k = 0; k < 8; ++k)
            xs[k] = *(const __half2*)(x + (size_t)cc[k] * EMB + l32 * 2);
#pragma unroll
        for (int k = 0; k < 8; ++k) {
            float2 xf = __half22float2(xs[k]);
            sx += vv[k] * xf.x;
            sy += vv[k] * xf.y;
        }
    }
    if (valid) {
        size_t o = (size_t)rc * EMB + l32 * 2;
        __half2 h = __floats2half2_rn(sx, sy);
        __builtin_nontemporal_store(*(int*)&h, (int*)(nxt + o));
    }
}

__global__ void k_spmm_last(const int* __restrict__ row_start, const PEdge* __restrict__ pe,
                            const __half* __restrict__ x2, const __half* __restrict__ xh1,
                            const float* __restrict__ ue, const float* __restrict__ ie, int nu,
                            float* __restrict__ acc, int n) {
    long gid = (long)blockIdx.x * blockDim.x + threadIdx.x;
    int wave = (int)(gid >> 6);
    int lane = threadIdx.x & 63;
    int half = lane >> 5;
    int l32  = lane & 31;
    int r = wave * 2 + half;
    if (wave * 2 >= n) return;
    bool valid = r < n;
    int rc = valid ? r : n - 1;
    int s = row_start[rc];
    int e = row_start[rc + 1];
    float sx = 0.f, sy = 0.f;
    for (int j = s; j < e; j += 8) {
        int cc[8]; float vv[8];
#pragma unroll
        for (int k = 0; k < 8; ++k) {
            int jj = j + k;
            bool ok = jj < e;
            unsigned u = pe[ok ? jj : j];
            cc[k] = (int)(u >> 13);
            vv[k] = ok ? (float)(u & 8191u) * VAL_INV : 0.f;
        }
        __half2 xs[8];
#pragma unroll
        for (int k = 0; k < 8; ++k)
            xs[k] = *(const __half2*)(x2 + (size_t)cc[k] * EMB + l32 * 2);
#pragma unroll
        for (int k = 0; k < 8; ++k) {
            float2 xf = __half22float2(xs[k]);
            sx += vv[k] * xf.x;
            sy += vv[k] * xf.y;
        }
    }
    if (valid) {
        size_t o = (size_t)rc * EMB + l32 * 2;
        const float* p = (rc < nu) ? (ue + (size_t)rc * EMB) : (ie + (size_t)(rc - nu) * EMB);
        float2 e0 = *(const float2*)(p + l32 * 2);
        float2 e1 = __half22float2(*(const __half2*)(xh1 + o));
        float2 e2 = __half22float2(*(const __half2*)(x2 + o));
        float2 rr;
        rr.x = (e0.x + e1.x + e2.x + sx) * 0.25f;
        rr.y = (e0.y + e1.y + e2.y + sy) * 0.25f;
        __builtin_nontemporal_store(*(double*)&rr, (double*)(acc + o));
    }
}

// ---------- fallback (R1 atomic path, fp32) ----------
__global__ void lgcn_init(const float4* __restrict__ ue, const float4* __restrict__ ie,
                          float4* __restrict__ emb, float4* __restrict__ acc,
                          long nu4, long ni4) {
    long total = nu4 + ni4;
    long stride = (long)gridDim.x * blockDim.x;
    for (long i = (long)blockIdx.x * blockDim.x + threadIdx.x; i < total; i += stride) {
        float4 v = (i < nu4) ? ue[i] : ie[i - nu4];
        emb[i] = v;
        acc[i] = v;
    }
}

__global__ void lgcn_spmm_atomic(const float* __restrict__ vals, const int* __restrict__ rows,
                                 const int* __restrict__ cols, const float* __restrict__ x,
                                 float* __restrict__ y, int ne) {
    long gid = (long)blockIdx.x * blockDim.x + threadIdx.x;
    int e = (int)(gid >> 6);
    int lane = (int)(gid & 63);
    if (e >= ne) return;
    float xv = x[(size_t)cols[e] * EMB + lane];
    atomicAdd(&y[(size_t)rows[e] * EMB + lane], vals[e] * xv);
}

__global__ void lgcn_acc(const float4* __restrict__ src, float4* __restrict__ acc,
                         long n4, float scale) {
    long stride = (long)gridDim.x * blockDim.x;
    for (long i = (long)blockIdx.x * blockDim.x + threadIdx.x; i < n4; i += stride) {
        float4 a = acc[i];
        float4 s = src[i];
        a.x = (a.x + s.x) * scale;
        a.y = (a.y + s.y) * scale;
        a.z = (a.z + s.z) * scale;
        a.w = (a.w + s.w) * scale;
        acc[i] = a;
    }
}

extern "C" void kernel_launch(void* const* d_in, const int* in_sizes, int n_in,
                              void* d_out, int out_size, void* d_ws, size_t ws_size,
                              hipStream_t stream) {
    const float* ue   = (const float*)d_in[0];
    const float* ie   = (const float*)d_in[1];
    const float* vals = (const float*)d_in[2];
    const int*   rows = (const int*)d_in[3];
    const int*   cols = (const int*)d_in[4];

    const int nu = in_sizes[0] / EMB;
    const int ni = in_sizes[1] / EMB;
    const int ne = in_sizes[2];
    const long n = (long)nu + ni;
    const size_t hbuf_bytes = (size_t)n * EMB * sizeof(__half);

    float* acc = (float*)d_out;

    // workspace carve
    char* p = (char*)d_ws;
    __half* xh0 = (__half*)p;    p += hbuf_bytes;
    __half* xh1 = (__half*)p;    p += hbuf_bytes;
    __half* xh2 = (__half*)p;    p += hbuf_bytes;
    PEdge* pe   = (PEdge*)p;     p += (size_t)ne * sizeof(PEdge);
    int*   row_start = (int*)p;  p += (size_t)(n + 1) * sizeof(int);
    int*   cursor = (int*)p;     p += (size_t)n * sizeof(int);
    int nb = (int)((n + SCAN_ELEMS - 1) / SCAN_ELEMS);
    int*   bsums = (int*)p;      p += (size_t)nb * sizeof(int);
    int*   bexcl = (int*)p;      p += (size_t)nb * sizeof(int);
    size_t needed = (size_t)(p - (char*)d_ws);

    const long nu4 = (long)nu * (EMB / 4);
    const long ni4 = (long)ni * (EMB / 4);

    if (needed <= ws_size && nb <= SCAN_TPB) {
        // ---- 1) CSR build (R13: sharded hist + sharded scatter) ----
        (void)hipMemsetAsync(cursor, 0, (size_t)n * sizeof(int), stream);
        k_hist<<<2048, 256, 0, stream>>>(rows, cursor, ne);
        k_scan1<<<nb, SCAN_TPB, 0, stream>>>(cursor, row_start, bsums, (int)n);
        k_scan2<<<1, SCAN_TPB, 0, stream>>>(bsums, bexcl, nb);
        k_scan3<<<nb, SCAN_TPB, 0, stream>>>(row_start, cursor, bexcl, (int)n, ne);
        k_scatter<<<2048, 256, 0, stream>>>(rows, cols, vals, cursor, pe, ne);

        // ---- 2) fp16 buffers: defensive zero (call-invariance) + input cvt ----
        (void)hipMemsetAsync(xh0, 0, hbuf_bytes * 3, stream);
        k_cvt<<<2048, 256, 0, stream>>>((const float4*)ue, (const float4*)ie,
                                        (__half2*)xh0, nu4, ni4);

        // ---- 3) 3 SpMM layers; 2 rows per wave; acc deferred to last ----
        long waves = (n + 1) / 2;
        int blocks = (int)((waves * 64 + 255) / 256);
        k_spmm_mid<<<blocks, 256, 0, stream>>>(row_start, pe, xh0, xh1, (int)n);
        k_spmm_mid<<<blocks, 256, 0, stream>>>(row_start, pe, xh1, xh2, (int)n);
        k_spmm_last<<<blocks, 256, 0, stream>>>(row_start, pe, xh2, xh1, ue, ie, nu,
                                                acc, (int)n);
    } else {
        // ---- fallback: R1 atomic path (fp32) ----
        const size_t buf_bytes = (size_t)n * EMB * sizeof(float);
        float* buf0 = (float*)d_ws;
        float* buf1 = (float*)((char*)d_ws + buf_bytes);
        const long n4 = n * (EMB / 4);
        lgcn_init<<<2048, 256, 0, stream>>>((const float4*)ue, (const float4*)ie,
                                            (float4*)buf0, (float4*)acc, nu4, ni4);
        float* cur = buf0;
        float* nxt = buf1;
        for (int l = 0; l < 3; ++l) {
            (void)hipMemsetAsync(nxt, 0, buf_bytes, stream);
            long threads = (long)ne * 64;
            int blk = (int)((threads + 255) / 256);
            lgcn_spmm_atomic<<<blk, 256, 0, stream>>>(vals, rows, cols, cur, nxt, ne);
            float scale = (l == 2) ? 0.25f : 1.0f;
            lgcn_acc<<<2048, 256, 0, stream>>>((const float4*)nxt, (float4*)acc, n4, scale);
            float* t = cur; cur = nxt; nxt = t;
        }
    }
}

// Round 16
// 645.190 us; speedup vs baseline: 1.4132x; 1.0393x over previous
//
#include <hip/hip_runtime.h>
#include <hip/hip_fp16.h>

#define EMB 64
#define SCAN_TPB 256
#define SCAN_EPT 8
#define SCAN_ELEMS (SCAN_TPB * SCAN_EPT)  // 2048

// Packed edge: (col << 13) | q, where val = q / 81920.0  (val in [0,0.1) per spec)
typedef unsigned int PEdge;
#define VAL_SCALE 81920.0f
#define VAL_INV   (1.0f / 81920.0f)

typedef unsigned int vu2 __attribute__((ext_vector_type(2)));
typedef float        vf4 __attribute__((ext_vector_type(4)));

// Shard key: cursor line granule (16 rows) -> one XCD owns each line.
__device__ __forceinline__ int row_shard(int r) { return (r >> 4) & 7; }

template <typename T>
__device__ __forceinline__ T ntload(const T* p) { return __builtin_nontemporal_load(p); }

// ---------- convert fp32 concat(ue,ie) -> fp16 x buffer ----------
__global__ void k_cvt(const float4* __restrict__ ue, const float4* __restrict__ ie,
                      __half2* __restrict__ xh2, long nu4, long ni4) {
    long total = nu4 + ni4;  // units of 4 floats
    long stride = (long)gridDim.x * blockDim.x;
    for (long i = (long)blockIdx.x * blockDim.x + threadIdx.x; i < total; i += stride) {
        float4 v = (i < nu4) ? ue[i] : ie[i - nu4];
        xh2[i * 2]     = __floats2half2_rn(v.x, v.y);
        xh2[i * 2 + 1] = __floats2half2_rn(v.z, v.w);
    }
}

// ---------- hist: UNSHARDED single pass (fire-and-forget atomics) ----------
// No return-value latency chain -> no need for cursor L2 residency; reads rows
// once (16 MB) instead of 8x. Plain loads keep rows L3-warm for the scatter.
__global__ void k_hist(const int* __restrict__ rows, int* __restrict__ cnt, int ne) {
    int stride = gridDim.x * blockDim.x;
    for (int e = blockIdx.x * blockDim.x + threadIdx.x; e < ne; e += stride)
        atomicAdd(&cnt[rows[e]], 1);
}

// ---------- scatter (R13: XCD-sharded, nt streaming reads) ----------
__global__ void k_scatter(const int* __restrict__ rows, const int* __restrict__ cols,
                          const float* __restrict__ vals, int* __restrict__ cursor,
                          PEdge* __restrict__ pe, int ne) {
    int g  = blockIdx.x & 7;
    int lt = (blockIdx.x >> 3) * blockDim.x + threadIdx.x;
    int gs = (gridDim.x >> 3) * blockDim.x;
    for (int e = lt; e < ne; e += gs) {
        int r = ntload(rows + e);
        if (row_shard(r) == g) {
            int p = atomicAdd(&cursor[r], 1);
            unsigned q = (unsigned)(ntload(vals + e) * VAL_SCALE + 0.5f);
            if (q > 8191u) q = 8191u;
            pe[p] = ((unsigned)ntload(cols + e) << 13) | q;
        }
    }
}

__global__ void k_scan1(const int* __restrict__ in, int* __restrict__ excl,
                        int* __restrict__ bsums, int n) {
    __shared__ int sh[SCAN_TPB];
    int t = threadIdx.x;
    int base = blockIdx.x * SCAN_ELEMS + t * SCAN_EPT;
    int v[SCAN_EPT];
    int ts = 0;
#pragma unroll
    for (int k = 0; k < SCAN_EPT; ++k) {
        v[k] = (base + k < n) ? in[base + k] : 0;
        ts += v[k];
    }
    sh[t] = ts;
    __syncthreads();
    for (int off = 1; off < SCAN_TPB; off <<= 1) {
        int x = (t >= off) ? sh[t - off] : 0;
        __syncthreads();
        sh[t] += x;
        __syncthreads();
    }
    int run = sh[t] - ts;
#pragma unroll
    for (int k = 0; k < SCAN_EPT; ++k) {
        if (base + k < n) excl[base + k] = run;
        run += v[k];
    }
    if (t == SCAN_TPB - 1) bsums[blockIdx.x] = sh[t];
}

__global__ void k_scan2(const int* __restrict__ bsums, int* __restrict__ bexcl, int nb) {
    __shared__ int sh[SCAN_TPB];
    int t = threadIdx.x;
    int ts = (t < nb) ? bsums[t] : 0;
    sh[t] = ts;
    __syncthreads();
    for (int off = 1; off < SCAN_TPB; off <<= 1) {
        int x = (t >= off) ? sh[t - off] : 0;
        __syncthreads();
        sh[t] += x;
        __syncthreads();
    }
    if (t < nb) bexcl[t] = sh[t] - ts;
}

__global__ void k_scan3(int* __restrict__ row_start, int* __restrict__ cursor,
                        const int* __restrict__ bexcl, int n, int ne) {
    int base = blockIdx.x * SCAN_ELEMS + threadIdx.x * SCAN_EPT;
    int off = bexcl[blockIdx.x];
#pragma unroll
    for (int k = 0; k < SCAN_EPT; ++k) {
        if (base + k < n) {
            int v = row_start[base + k] + off;
            row_start[base + k] = v;
            cursor[base + k] = v;
        }
    }
    if (blockIdx.x == 0 && threadIdx.x == 0) row_start[n] = ne;
}

// ---------- SpMM: FOUR rows per wave (16-lane quarters, 8B = 4 fp16 dims/lane) ----
// One gather instruction serves 4 rows. Pad slots reuse slot-0 (L1-hot).
__global__ void k_spmm_mid(const int* __restrict__ row_start, const PEdge* __restrict__ pe,
                           const __half* __restrict__ x, __half* __restrict__ nxt, int n) {
    long gid = (long)blockIdx.x * blockDim.x + threadIdx.x;
    int wave = (int)(gid >> 6);
    int lane = threadIdx.x & 63;
    int quad = lane >> 4;
    int l16  = lane & 15;
    int r = wave * 4 + quad;
    if (wave * 4 >= n) return;
    bool valid = r < n;
    int rc = valid ? r : n - 1;
    int s = row_start[rc];
    int e = row_start[rc + 1];
    float sx = 0.f, sy = 0.f, sz = 0.f, sw = 0.f;
    for (int j = s; j < e; j += 8) {
        int cc[8]; float vv[8];
#pragma unroll
        for (int k = 0; k < 8; ++k) {
            int jj = j + k;
            bool ok = jj < e;
            unsigned u = pe[ok ? jj : j];
            cc[k] = (int)(u >> 13);
            vv[k] = ok ? (float)(u & 8191u) * VAL_INV : 0.f;
        }
        vu2 xs[8];
#pragma unroll
        for (int k = 0; k < 8; ++k)
            xs[k] = *(const vu2*)(x + (size_t)cc[k] * EMB + l16 * 4);
#pragma unroll
        for (int k = 0; k < 8; ++k) {
            unsigned a = xs[k].x, b = xs[k].y;
            float2 fa = __half22float2(*(__half2*)&a);
            float2 fb = __half22float2(*(__half2*)&b);
            sx += vv[k] * fa.x;
            sy += vv[k] * fa.y;
            sz += vv[k] * fb.x;
            sw += vv[k] * fb.y;
        }
    }
    if (valid) {
        size_t o = (size_t)rc * EMB + l16 * 4;
        __half2 h0 = __floats2half2_rn(sx, sy);
        __half2 h1 = __floats2half2_rn(sz, sw);
        vu2 ov;
        ov.x = *(unsigned*)&h0;
        ov.y = *(unsigned*)&h1;
        __builtin_nontemporal_store(ov, (vu2*)(nxt + o));
    }
}

__global__ void k_spmm_last(const int* __restrict__ row_start, const PEdge* __restrict__ pe,
                            const __half* __restrict__ x2, const __half* __restrict__ xh1,
                            const float* __restrict__ ue, const float* __restrict__ ie, int nu,
                            float* __restrict__ acc, int n) {
    long gid = (long)blockIdx.x * blockDim.x + threadIdx.x;
    int wave = (int)(gid >> 6);
    int lane = threadIdx.x & 63;
    int quad = lane >> 4;
    int l16  = lane & 15;
    int r = wave * 4 + quad;
    if (wave * 4 >= n) return;
    bool valid = r < n;
    int rc = valid ? r : n - 1;
    int s = row_start[rc];
    int e = row_start[rc + 1];
    float sx = 0.f, sy = 0.f, sz = 0.f, sw = 0.f;
    for (int j = s; j < e; j += 8) {
        int cc[8]; float vv[8];
#pragma unroll
        for (int k = 0; k < 8; ++k) {
            int jj = j + k;
            bool ok = jj < e;
            unsigned u = pe[ok ? jj : j];
            cc[k] = (int)(u >> 13);
            vv[k] = ok ? (float)(u & 8191u) * VAL_INV : 0.f;
        }
        vu2 xs[8];
#pragma unroll
        for (int k = 0; k < 8; ++k)
            xs[k] = *(const vu2*)(x2 + (size_t)cc[k] * EMB + l16 * 4);
#pragma unroll
        for (int k = 0; k < 8; ++k) {
            unsigned a = xs[k].x, b = xs[k].y;
            float2 fa = __half22float2(*(__half2*)&a);
            float2 fb = __half22float2(*(__half2*)&b);
            sx += vv[k] * fa.x;
            sy += vv[k] * fa.y;
            sz += vv[k] * fb.x;
            sw += vv[k] * fb.y;
        }
    }
    if (valid) {
        size_t o = (size_t)rc * EMB + l16 * 4;
        const float* p = (rc < nu) ? (ue + (size_t)rc * EMB) : (ie + (size_t)(rc - nu) * EMB);
        float4 e0 = *(const float4*)(p + l16 * 4);
        vu2 u1 = *(const vu2*)(xh1 + o);
        vu2 u2 = *(const vu2*)(x2 + o);
        unsigned a1 = u1.x, b1 = u1.y, a2 = u2.x, b2 = u2.y;
        float2 e1a = __half22float2(*(__half2*)&a1);
        float2 e1b = __half22float2(*(__half2*)&b1);
        float2 e2a = __half22float2(*(__half2*)&a2);
        float2 e2b = __half22float2(*(__half2*)&b2);
        vf4 rr;
        rr.x = (e0.x + e1a.x + e2a.x + sx) * 0.25f;
        rr.y = (e0.y + e1a.y + e2a.y + sy) * 0.25f;
        rr.z = (e0.z + e1b.x + e2b.x + sz) * 0.25f;
        rr.w = (e0.w + e1b.y + e2b.y + sw) * 0.25f;
        __builtin_nontemporal_store(rr, (vf4*)(acc + o));
    }
}

// ---------- fallback (R1 atomic path, fp32) ----------
__global__ void lgcn_init(const float4* __restrict__ ue, const float4* __restrict__ ie,
                          float4* __restrict__ emb, float4* __restrict__ acc,
                          long nu4, long ni4) {
    long total = nu4 + ni4;
    long stride = (long)gridDim.x * blockDim.x;
    for (long i = (long)blockIdx.x * blockDim.x + threadIdx.x; i < total; i += stride) {
        float4 v = (i < nu4) ? ue[i] : ie[i - nu4];
        emb[i] = v;
        acc[i] = v;
    }
}

__global__ void lgcn_spmm_atomic(const float* __restrict__ vals, const int* __restrict__ rows,
                                 const int* __restrict__ cols, const float* __restrict__ x,
                                 float* __restrict__ y, int ne) {
    long gid = (long)blockIdx.x * blockDim.x + threadIdx.x;
    int e = (int)(gid >> 6);
    int lane = (int)(gid & 63);
    if (e >= ne) return;
    float xv = x[(size_t)cols[e] * EMB + lane];
    atomicAdd(&y[(size_t)rows[e] * EMB + lane], vals[e] * xv);
}

__global__ void lgcn_acc(const float4* __restrict__ src, float4* __restrict__ acc,
                         long n4, float scale) {
    long stride = (long)gridDim.x * blockDim.x;
    for (long i = (long)blockIdx.x * blockDim.x + threadIdx.x; i < n4; i += stride) {
        float4 a = acc[i];
        float4 s = src[i];
        a.x = (a.x + s.x) * scale;
        a.y = (a.y + s.y) * scale;
        a.z = (a.z + s.z) * scale;
        a.w = (a.w + s.w) * scale;
        acc[i] = a;
    }
}

extern "C" void kernel_launch(void* const* d_in, const int* in_sizes, int n_in,
                              void* d_out, int out_size, void* d_ws, size_t ws_size,
                              hipStream_t stream) {
    const float* ue   = (const float*)d_in[0];
    const float* ie   = (const float*)d_in[1];
    const float* vals = (const float*)d_in[2];
    const int*   rows = (const int*)d_in[3];
    const int*   cols = (const int*)d_in[4];

    const int nu = in_sizes[0] / EMB;
    const int ni = in_sizes[1] / EMB;
    const int ne = in_sizes[2];
    const long n = (long)nu + ni;
    const size_t hbuf_bytes = (size_t)n * EMB * sizeof(__half);

    float* acc = (float*)d_out;

    // workspace carve
    char* p = (char*)d_ws;
    __half* xh0 = (__half*)p;    p += hbuf_bytes;
    __half* xh1 = (__half*)p;    p += hbuf_bytes;
    __half* xh2 = (__half*)p;    p += hbuf_bytes;
    PEdge* pe   = (PEdge*)p;     p += (size_t)ne * sizeof(PEdge);
    int*   row_start = (int*)p;  p += (size_t)(n + 1) * sizeof(int);
    int*   cursor = (int*)p;     p += (size_t)n * sizeof(int);
    int nb = (int)((n + SCAN_ELEMS - 1) / SCAN_ELEMS);
    int*   bsums = (int*)p;      p += (size_t)nb * sizeof(int);
    int*   bexcl = (int*)p;      p += (size_t)nb * sizeof(int);
    size_t needed = (size_t)(p - (char*)d_ws);

    const long nu4 = (long)nu * (EMB / 4);
    const long ni4 = (long)ni * (EMB / 4);

    if (needed <= ws_size && nb <= SCAN_TPB) {
        // ---- 1) CSR build (unsharded 1-pass hist; sharded scatter) ----
        (void)hipMemsetAsync(cursor, 0, (size_t)n * sizeof(int), stream);
        k_hist<<<2048, 256, 0, stream>>>(rows, cursor, ne);
        k_scan1<<<nb, SCAN_TPB, 0, stream>>>(cursor, row_start, bsums, (int)n);
        k_scan2<<<1, SCAN_TPB, 0, stream>>>(bsums, bexcl, nb);
        k_scan3<<<nb, SCAN_TPB, 0, stream>>>(row_start, cursor, bexcl, (int)n, ne);
        k_scatter<<<2048, 256, 0, stream>>>(rows, cols, vals, cursor, pe, ne);

        // ---- 2) fp16 buffers: defensive zero (call-invariance) + input cvt ----
        (void)hipMemsetAsync(xh0, 0, hbuf_bytes * 3, stream);
        k_cvt<<<2048, 256, 0, stream>>>((const float4*)ue, (const float4*)ie,
                                        (__half2*)xh0, nu4, ni4);

        // ---- 3) 3 SpMM layers; 4 rows per wave; acc deferred to last ----
        long waves = (n + 3) / 4;
        int blocks = (int)((waves * 64 + 255) / 256);
        k_spmm_mid<<<blocks, 256, 0, stream>>>(row_start, pe, xh0, xh1, (int)n);
        k_spmm_mid<<<blocks, 256, 0, stream>>>(row_start, pe, xh1, xh2, (int)n);
        k_spmm_last<<<blocks, 256, 0, stream>>>(row_start, pe, xh2, xh1, ue, ie, nu,
                                                acc, (int)n);
    } else {
        // ---- fallback: R1 atomic path (fp32) ----
        const size_t buf_bytes = (size_t)n * EMB * sizeof(float);
        float* buf0 = (float*)d_ws;
        float* buf1 = (float*)((char*)d_ws + buf_bytes);
        const long n4 = n * (EMB / 4);
        lgcn_init<<<2048, 256, 0, stream>>>((const float4*)ue, (const float4*)ie,
                                            (float4*)buf0, (float4*)acc, nu4, ni4);
        float* cur = buf0;
        float* nxt = buf1;
        for (int l = 0; l < 3; ++l) {
            (void)hipMemsetAsync(nxt, 0, buf_bytes, stream);
            long threads = (long)ne * 64;
            int blk = (int)((threads + 255) / 256);
            lgcn_spmm_atomic<<<blk, 256, 0, stream>>>(vals, rows, cols, cur, nxt, ne);
            float scale = (l == 2) ? 0.25f : 1.0f;
            lgcn_acc<<<2048, 256, 0, stream>>>((const float4*)nxt, (float4*)acc, n4, scale);
            float* t = cur; cur = nxt; nxt = t;
        }
    }
}